// Round 5
// baseline (109.629 us; speedup 1.0000x reference)
//
#include <hip/hip_runtime.h>
#include <hip/hip_bf16.h>

typedef __bf16 bf16x8 __attribute__((ext_vector_type(8)));
typedef __bf16 bf16x4 __attribute__((ext_vector_type(4)));
typedef float  f32x4  __attribute__((ext_vector_type(4)));

constexpr int Bn = 8192, Dn = 64, On = 256;

// ---- prep: betasT bf16 [O][e][d] (A-operand layout) + NEGATED c_proj fp32 ----
__global__ void k_prep_beta(const float* __restrict__ betas, const float* __restrict__ centers,
                            __bf16* __restrict__ bT, float* __restrict__ ncproj) {
    __shared__ float s[64 * 65];                        // +1 pad: conflict-free transpose
    const int o = blockIdx.x, tid = threadIdx.x;
    const float* bo = betas + (size_t)o * 4096;         // betas[o][d][e]
    for (int j = tid; j < 1024; j += 256) {             // float4 quads over [d][e]
        int d = j >> 4, e = (j & 15) * 4;
        float4 v = ((const float4*)bo)[j];
        s[d * 65 + e + 0] = v.x; s[d * 65 + e + 1] = v.y;
        s[d * 65 + e + 2] = v.z; s[d * 65 + e + 3] = v.w;
    }
    __syncthreads();
    for (int j = tid; j < 1024; j += 256) {             // quads over [e][d]
        int e = j >> 4, d = (j & 15) * 4;
        bf16x4 r;
        r[0] = (__bf16)s[(d + 0) * 65 + e]; r[1] = (__bf16)s[(d + 1) * 65 + e];
        r[2] = (__bf16)s[(d + 2) * 65 + e]; r[3] = (__bf16)s[(d + 3) * 65 + e];
        *(bf16x4*)(bT + (size_t)o * 4096 + e * 64 + d) = r;
    }
    if (tid < 64) {
        float acc = 0.f;
        for (int d = 0; d < 64; ++d) acc += s[d * 65 + tid] * centers[o * 64 + d];
        ncproj[o * 64 + tid] = -acc;                    // negated: MFMA C-init
    }
}

// ---- main: wave = 64 b x 8 o. No LDS, no barriers, no double-buffer.
//      ~110 VGPR -> 4 waves/SIMD; grid 1024 = 4 blocks/CU, single round.
//      Occupancy (16 waves/CU) hides the per-o L2 A-frag latency (m114). ----
__global__ __launch_bounds__(256, 4) void k_main(const float* __restrict__ x,
                                                 const __bf16* __restrict__ bT,
                                                 const float* __restrict__ ncproj,
                                                 float* __restrict__ out) {
    const int tid  = threadIdx.x;
    const int wq   = tid >> 6, lane = tid & 63;
    const int col  = lane & 15, grp = lane >> 4;
    const int bbase = blockIdx.x * 256 + wq * 64;       // 64 b per wave
    const int o0    = blockIdx.y * 8;

    // x fragments: lane holds x[bbase+nf*16+col][grp*8 + ks*32 .. +7], bf16
    bf16x8 xf[4][2];
#pragma unroll
    for (int nf = 0; nf < 4; ++nf) {
        const float* xp = x + (size_t)(bbase + nf * 16 + col) * 64 + grp * 8;
#pragma unroll
        for (int ks = 0; ks < 2; ++ks) {
            float4 v0 = *(const float4*)(xp + ks * 32);
            float4 v1 = *(const float4*)(xp + ks * 32 + 4);
            bf16x8 f;
            f[0] = (__bf16)v0.x; f[1] = (__bf16)v0.y; f[2] = (__bf16)v0.z; f[3] = (__bf16)v0.w;
            f[4] = (__bf16)v1.x; f[5] = (__bf16)v1.y; f[6] = (__bf16)v1.z; f[7] = (__bf16)v1.w;
            xf[nf][ks] = f;
        }
    }

    float q8[8];
#pragma unroll
    for (int oi = 0; oi < 8; ++oi) {
        // single A-frag buffer for this o (48 VGPR live)
        const __bf16* p = bT + (size_t)(o0 + oi) * 4096 + (size_t)col * 64 + grp * 8;
        const float*  c = ncproj + (o0 + oi) * 64 + grp * 4;
        bf16x8 a0[4], a1[4];
        f32x4  ncp[4];
#pragma unroll
        for (int mi = 0; mi < 4; ++mi) {
            a0[mi]  = *(const bf16x8*)(p + mi * 1024);
            a1[mi]  = *(const bf16x8*)(p + mi * 1024 + 32);
            ncp[mi] = *(const f32x4*)(c + mi * 16);     // e = mi*16 + grp*4 + r
        }
#pragma unroll
        for (int nf = 0; nf < 4; ++nf) {
            f32x4 qv = {0.f, 0.f, 0.f, 0.f};
#pragma unroll
            for (int mi = 0; mi < 4; ++mi) {
                f32x4 acc = ncp[mi];                    // C-init = -cp -> acc = y - cp
                acc = __builtin_amdgcn_mfma_f32_16x16x32_bf16(a0[mi], xf[nf][0], acc, 0, 0, 0);
                acc = __builtin_amdgcn_mfma_f32_16x16x32_bf16(a1[mi], xf[nf][1], acc, 0, 0, 0);
                qv += acc * acc;                        // packed fp32
            }
            float qs = (qv[0] + qv[1]) + (qv[2] + qv[3]);
            qs += __shfl_xor(qs, 16, 64);               // full e-sum in every lane
            qs += __shfl_xor(qs, 32, 64);
            if (grp == nf) q8[oi] = qs;                 // lane keeps its designated row
        }
    }

    // epilogue: lane (col,grp) owns row b = bbase + grp*16 + col, o = o0..o0+7
    f32x4 r0, r1;
#pragma unroll
    for (int j = 0; j < 4; ++j) { r0[j] = __expf(-q8[j]); r1[j] = __expf(-q8[4 + j]); }
    float* op = out + (size_t)(bbase + grp * 16 + col) * 256 + o0;
    *(f32x4*)op       = r0;                             // 32 B contiguous per lane
    *(f32x4*)(op + 4) = r1;
}

extern "C" void kernel_launch(void* const* d_in, const int* in_sizes, int n_in,
                              void* d_out, int out_size, void* d_ws, size_t ws_size,
                              hipStream_t stream) {
    const float* x       = (const float*)d_in[0];   // [8192,64]
    const float* centers = (const float*)d_in[1];   // [256,1,64]
    const float* betas   = (const float*)d_in[2];   // [256,64,64]
    float* out = (float*)d_out;                     // [8192,256] fp32

    char* ws = (char*)d_ws;
    __bf16* bT   = (__bf16*)ws;                     // 2 MB
    float*  ncpj = (float*)(ws + 2 * (1 << 20));    // 64 KB

    k_prep_beta<<<dim3(On),               dim3(256), 0, stream>>>(betas, centers, bT, ncpj);
    k_main     <<<dim3(Bn / 256, On / 8), dim3(256), 0, stream>>>(x, bT, ncpj, out);
}

// Round 6
// 89.421 us; speedup vs baseline: 1.2260x; 1.2260x over previous
//
#include <hip/hip_runtime.h>
#include <hip/hip_bf16.h>

typedef __bf16 bf16x8 __attribute__((ext_vector_type(8)));
typedef __bf16 bf16x4 __attribute__((ext_vector_type(4)));
typedef float  f32x4  __attribute__((ext_vector_type(4)));

constexpr int Bn = 8192, Dn = 64, On = 256;

// ---- prep: betasT bf16 [O][e][d] (A-operand layout) + NEGATED c_proj fp32 ----
__global__ void k_prep_beta(const float* __restrict__ betas, const float* __restrict__ centers,
                            __bf16* __restrict__ bT, float* __restrict__ ncproj) {
    __shared__ float s[64 * 65];                        // +1 pad: conflict-free transpose
    const int o = blockIdx.x, tid = threadIdx.x;
    const float* bo = betas + (size_t)o * 4096;         // betas[o][d][e]
    for (int j = tid; j < 1024; j += 256) {             // float4 quads over [d][e]
        int d = j >> 4, e = (j & 15) * 4;
        float4 v = ((const float4*)bo)[j];
        s[d * 65 + e + 0] = v.x; s[d * 65 + e + 1] = v.y;
        s[d * 65 + e + 2] = v.z; s[d * 65 + e + 3] = v.w;
    }
    __syncthreads();
    for (int j = tid; j < 1024; j += 256) {             // quads over [e][d]
        int e = j >> 4, d = (j & 15) * 4;
        bf16x4 r;
        r[0] = (__bf16)s[(d + 0) * 65 + e]; r[1] = (__bf16)s[(d + 1) * 65 + e];
        r[2] = (__bf16)s[(d + 2) * 65 + e]; r[3] = (__bf16)s[(d + 3) * 65 + e];
        *(bf16x4*)(bT + (size_t)o * 4096 + e * 64 + d) = r;
    }
    if (tid < 64) {
        float acc = 0.f;
        for (int d = 0; d < 64; ++d) acc += s[d * 65 + tid] * centers[o * 64 + d];
        ncproj[o * 64 + tid] = -acc;                    // negated: MFMA C-init
    }
}

// ---- main: wave = 64 b x 4 o. A (betaT) staged in LDS once (1 barrier);
//      hot loop touches ONLY LDS + registers -> demotion-proof. ----
__global__ __launch_bounds__(256, 4) void k_main(const float* __restrict__ x,
                                                 const __bf16* __restrict__ bT,
                                                 const float* __restrict__ ncproj,
                                                 float* __restrict__ out) {
    __shared__ __align__(16) __bf16 sA[4 * 64 * 72];    // [o'][e=64][72 pad] = 36 KB
    __shared__ float sC[4 * 64];                        // negated c_proj

    const int tid  = threadIdx.x;
    const int wq   = tid >> 6, lane = tid & 63;
    const int col  = lane & 15, grp = lane >> 4;
    const int bbase = blockIdx.x * 256 + wq * 64;
    const int o0    = blockIdx.y * 4;

    // x fragments: lane(col,grp) holds x[bbase+nf*16+col][ks*32 + grp*8 ..+7]
    bf16x8 xf[4][2];
#pragma unroll
    for (int nf = 0; nf < 4; ++nf) {
        const float* xp = x + (size_t)(bbase + nf * 16 + col) * 64 + grp * 8;
#pragma unroll
        for (int ks = 0; ks < 2; ++ks) {
            float4 v0 = *(const float4*)(xp + ks * 32);
            float4 v1 = *(const float4*)(xp + ks * 32 + 4);
            bf16x8 f;
            f[0] = (__bf16)v0.x; f[1] = (__bf16)v0.y; f[2] = (__bf16)v0.z; f[3] = (__bf16)v0.w;
            f[4] = (__bf16)v1.x; f[5] = (__bf16)v1.y; f[6] = (__bf16)v1.z; f[7] = (__bf16)v1.w;
            xf[nf][ks] = f;
        }
    }

    // stage bT[o0..o0+3] -> sA (rows padded 64->72), ncproj -> sC
    {
        const __bf16* src = bT + (size_t)o0 * 4096;     // 16 KB contiguous
#pragma unroll
        for (int i = 0; i < 8; ++i) {
            int ch = i * 256 + tid;                     // 16B chunk id, 0..2047
            int oe = ch >> 3, c = ch & 7;               // oe = o'*64+e
            bf16x8 v = *(const bf16x8*)(src + ch * 8);
            *(bf16x8*)(sA + oe * 72 + c * 8) = v;
        }
        sC[tid] = ncproj[o0 * 64 + tid];                // 4 o x 64 e
    }
    __syncthreads();                                    // the only barrier

    float q4[4];
#pragma unroll
    for (int oi = 0; oi < 4; ++oi) {
        const __bf16* A = sA + oi * 64 * 72;
        const float*  C = sC + oi * 64;
        bf16x8 a0[4], a1[4];
        f32x4  ncp[4];
#pragma unroll
        for (int mi = 0; mi < 4; ++mi) {                // ds_read_b128 x8 + bcast x4
            const __bf16* ar = A + (mi * 16 + col) * 72 + grp * 8;
            a0[mi]  = *(const bf16x8*)(ar);
            a1[mi]  = *(const bf16x8*)(ar + 32);
            ncp[mi] = *(const f32x4*)(C + mi * 16 + grp * 4);
        }
#pragma unroll
        for (int nf = 0; nf < 4; ++nf) {
            f32x4 qv = {0.f, 0.f, 0.f, 0.f};
#pragma unroll
            for (int mi = 0; mi < 4; ++mi) {
                f32x4 acc = ncp[mi];                    // C-init = -cp -> acc = y - cp
                acc = __builtin_amdgcn_mfma_f32_16x16x32_bf16(a0[mi], xf[nf][0], acc, 0, 0, 0);
                acc = __builtin_amdgcn_mfma_f32_16x16x32_bf16(a1[mi], xf[nf][1], acc, 0, 0, 0);
                qv += acc * acc;                        // packed fp32
            }
            float qs = (qv[0] + qv[1]) + (qv[2] + qv[3]);
            qs += __shfl_xor(qs, 16, 64);               // full e-sum in every lane
            qs += __shfl_xor(qs, 32, 64);
            if (grp == nf) q4[oi] = qs;                 // lane keeps its own row's q
        }
    }

    // epilogue: lane(col,grp) owns b = bbase + grp*16 + col; one 16 B store
    f32x4 r;
#pragma unroll
    for (int j = 0; j < 4; ++j) r[j] = __expf(-q4[j]);
    *(f32x4*)(out + (size_t)(bbase + grp * 16 + col) * 256 + o0) = r;
}

extern "C" void kernel_launch(void* const* d_in, const int* in_sizes, int n_in,
                              void* d_out, int out_size, void* d_ws, size_t ws_size,
                              hipStream_t stream) {
    const float* x       = (const float*)d_in[0];   // [8192,64]
    const float* centers = (const float*)d_in[1];   // [256,1,64]
    const float* betas   = (const float*)d_in[2];   // [256,64,64]
    float* out = (float*)d_out;                     // [8192,256] fp32

    char* ws = (char*)d_ws;
    __bf16* bT   = (__bf16*)ws;                     // 2 MB
    float*  ncpj = (float*)(ws + 2 * (1 << 20));    // 64 KB

    k_prep_beta<<<dim3(On),               dim3(256), 0, stream>>>(betas, centers, bT, ncpj);
    k_main     <<<dim3(Bn / 256, On / 4), dim3(256), 0, stream>>>(x, bT, ncpj, out);
}

// Round 7
// 89.272 us; speedup vs baseline: 1.2280x; 1.0017x over previous
//
#include <hip/hip_runtime.h>
#include <hip/hip_bf16.h>

typedef __bf16 bf16x8 __attribute__((ext_vector_type(8)));
typedef __bf16 bf16x4 __attribute__((ext_vector_type(4)));
typedef float  f32x4  __attribute__((ext_vector_type(4)));

constexpr int Bn = 8192, Dn = 64, On = 256;

// ---- prep: betasT bf16 [O][e][d] (A-operand layout) + NEGATED c_proj fp32 ----
__global__ void k_prep_beta(const float* __restrict__ betas, const float* __restrict__ centers,
                            __bf16* __restrict__ bT, float* __restrict__ ncproj) {
    __shared__ float s[64 * 65];                        // +1 pad: conflict-free transpose
    const int o = blockIdx.x, tid = threadIdx.x;
    const float* bo = betas + (size_t)o * 4096;         // betas[o][d][e]
    for (int j = tid; j < 1024; j += 256) {             // float4 quads over [d][e]
        int d = j >> 4, e = (j & 15) * 4;
        float4 v = ((const float4*)bo)[j];
        s[d * 65 + e + 0] = v.x; s[d * 65 + e + 1] = v.y;
        s[d * 65 + e + 2] = v.z; s[d * 65 + e + 3] = v.w;
    }
    __syncthreads();
    for (int j = tid; j < 1024; j += 256) {             // quads over [e][d]
        int e = j >> 4, d = (j & 15) * 4;
        bf16x4 r;
        r[0] = (__bf16)s[(d + 0) * 65 + e]; r[1] = (__bf16)s[(d + 1) * 65 + e];
        r[2] = (__bf16)s[(d + 2) * 65 + e]; r[3] = (__bf16)s[(d + 3) * 65 + e];
        *(bf16x4*)(bT + (size_t)o * 4096 + e * 64 + d) = r;
    }
    if (tid < 64) {
        float acc = 0.f;
        for (int d = 0; d < 64; ++d) acc += s[d * 65 + tid] * centers[o * 64 + d];
        ncproj[o * 64 + tid] = -acc;                    // negated: MFMA C-init
    }
}

// ---- main: block = 256 b x 2 o, 4 waves. BOTH operands LDS-staged with XOR
//      chunk swizzle (no pad, b128-floor banks, 16B aligned). Hot loop =
//      ds_read + MFMA only -> nothing can demote to a global load. ----
__global__ __launch_bounds__(256, 3) void k_main(const float* __restrict__ x,
                                                 const __bf16* __restrict__ bT,
                                                 const float* __restrict__ ncproj,
                                                 float* __restrict__ out) {
    __shared__ __align__(16) __bf16 sX[256 * 64];       // 32 KB, xor-swizzled chunks
    __shared__ __align__(16) __bf16 sA[128 * 64];       // 16 KB (2 o x 64 e)
    __shared__ float sC[128];                           // neg c_proj, 2 o

    const int tid = threadIdx.x;
    const int wq = tid >> 6, lane = tid & 63;
    const int col = lane & 15, grp = lane >> 4;
    const int bbase = blockIdx.x * 256;
    const int o0 = blockIdx.y * 2;

    // stage x fp32 -> bf16, chunk (row rb, c) at rb*64 + ((c^(rb&7))*8)
#pragma unroll
    for (int i = 0; i < 8; ++i) {
        int id = i * 256 + tid;                         // 2048 16B chunks
        int rb = id >> 3, c = id & 7;
        const float* xp = x + (size_t)(bbase + rb) * 64 + c * 8;
        float4 v0 = *(const float4*)xp;
        float4 v1 = *(const float4*)(xp + 4);
        bf16x8 f;
        f[0] = (__bf16)v0.x; f[1] = (__bf16)v0.y; f[2] = (__bf16)v0.z; f[3] = (__bf16)v0.w;
        f[4] = (__bf16)v1.x; f[5] = (__bf16)v1.y; f[6] = (__bf16)v1.z; f[7] = (__bf16)v1.w;
        *(bf16x8*)(sX + rb * 64 + ((c ^ (rb & 7)) << 3)) = f;
    }
    // stage A (bT rows are already bf16 A-layout), same swizzle
#pragma unroll
    for (int i = 0; i < 4; ++i) {
        int id = i * 256 + tid;                         // 1024 16B chunks
        int ar = id >> 3, c = id & 7;
        bf16x8 v = *(const bf16x8*)(bT + (size_t)o0 * 4096 + ar * 64 + c * 8);
        *(bf16x8*)(sA + ar * 64 + ((c ^ (ar & 7)) << 3)) = v;
    }
    if (tid < 128) sC[tid] = ncproj[o0 * 64 + tid];
    __syncthreads();                                    // the only barrier

    // swizzle key: rows used below are (mult of 16) + col -> r&7 == col&7
    const int sw0 = (grp ^ (col & 7)) << 3;             // chunk d=grp*8
    const int sw1 = ((grp ^ (col & 7)) ^ 4) << 3;       // chunk d=32+grp*8

    // x fragments from LDS (re-read is cheap even if demoted)
    bf16x8 xf[4][2];
#pragma unroll
    for (int nf = 0; nf < 4; ++nf) {
        const __bf16* xr = sX + (wq * 64 + nf * 16 + col) * 64;
        xf[nf][0] = *(const bf16x8*)(xr + sw0);
        xf[nf][1] = *(const bf16x8*)(xr + sw1);
    }

    float q2[2];
#pragma unroll
    for (int oi = 0; oi < 2; ++oi) {
        bf16x8 a0[4], a1[4];
        f32x4  ncp[4];
#pragma unroll
        for (int mi = 0; mi < 4; ++mi) {
            const __bf16* ar = sA + (oi * 64 + mi * 16 + col) * 64;
            a0[mi]  = *(const bf16x8*)(ar + sw0);
            a1[mi]  = *(const bf16x8*)(ar + sw1);
            ncp[mi] = *(const f32x4*)(sC + oi * 64 + mi * 16 + grp * 4);
        }
#pragma unroll
        for (int nf = 0; nf < 4; ++nf) {
            f32x4 qv = {0.f, 0.f, 0.f, 0.f};
#pragma unroll
            for (int mi = 0; mi < 4; ++mi) {
                f32x4 acc = ncp[mi];                    // C-init = -cp -> acc = y - cp
                acc = __builtin_amdgcn_mfma_f32_16x16x32_bf16(a0[mi], xf[nf][0], acc, 0, 0, 0);
                acc = __builtin_amdgcn_mfma_f32_16x16x32_bf16(a1[mi], xf[nf][1], acc, 0, 0, 0);
                qv += acc * acc;                        // packed fp32
            }
            float qs = (qv[0] + qv[1]) + (qv[2] + qv[3]);
            qs += __shfl_xor(qs, 16, 64);               // full e-sum in every lane
            qs += __shfl_xor(qs, 32, 64);
            if (grp == nf) q2[oi] = qs;                 // lane's own output row
        }
    }

    // lane(col,grp,wq) owns b = bbase + wq*64 + grp*16 + col; 8 B store, o0..o0+1
    float2 r;
    r.x = __expf(-q2[0]);
    r.y = __expf(-q2[1]);
    *(float2*)(out + (size_t)(bbase + wq * 64 + grp * 16 + col) * 256 + o0) = r;
}

extern "C" void kernel_launch(void* const* d_in, const int* in_sizes, int n_in,
                              void* d_out, int out_size, void* d_ws, size_t ws_size,
                              hipStream_t stream) {
    const float* x       = (const float*)d_in[0];   // [8192,64]
    const float* centers = (const float*)d_in[1];   // [256,1,64]
    const float* betas   = (const float*)d_in[2];   // [256,64,64]
    float* out = (float*)d_out;                     // [8192,256] fp32

    char* ws = (char*)d_ws;
    __bf16* bT   = (__bf16*)ws;                     // 2 MB
    float*  ncpj = (float*)(ws + 2 * (1 << 20));    // 64 KB

    k_prep_beta<<<dim3(On),               dim3(256), 0, stream>>>(betas, centers, bT, ncpj);
    k_main     <<<dim3(Bn / 256, On / 2), dim3(256), 0, stream>>>(x, bT, ncpj, out);
}

// Round 8
// 86.359 us; speedup vs baseline: 1.2695x; 1.0337x over previous
//
#include <hip/hip_runtime.h>
#include <hip/hip_bf16.h>

typedef __bf16 bf16x8 __attribute__((ext_vector_type(8)));
typedef float  f32x4  __attribute__((ext_vector_type(4)));
typedef float  f32x16 __attribute__((ext_vector_type(16)));

constexpr int Bn = 8192, Dn = 64, On = 256;

// async global->LDS DMA (not demotable by regalloc; dest = uniform base + lane*size)
#define GLD16(g, l) __builtin_amdgcn_global_load_lds( \
    (const __attribute__((address_space(1))) void*)(g), \
    (__attribute__((address_space(3))) void*)(l), 16, 0, 0)
#define GLD4(g, l) __builtin_amdgcn_global_load_lds( \
    (const __attribute__((address_space(1))) void*)(g), \
    (__attribute__((address_space(3))) void*)(l), 4, 0, 0)

// ---- prep: bTsw[o][e][slot] = betaT chunk-XOR-swizzled bf16 A-image;
//      ncpk[o][64] = -c_proj packed in 32x32 C-register order ----
__global__ void k_prep(const float* __restrict__ betas, const float* __restrict__ centers,
                       __bf16* __restrict__ bTsw, float* __restrict__ ncpk) {
    __shared__ float s[64 * 65];                        // +1 pad transpose buffer
    const int o = blockIdx.x, tid = threadIdx.x;
    const float* bo = betas + (size_t)o * 4096;         // betas[o][d][e]
    for (int j = tid; j < 1024; j += 256) {
        int d = j >> 4, e4 = (j & 15) * 4;
        float4 v = ((const float4*)bo)[j];
        s[d * 65 + e4 + 0] = v.x; s[d * 65 + e4 + 1] = v.y;
        s[d * 65 + e4 + 2] = v.z; s[d * 65 + e4 + 3] = v.w;
    }
    __syncthreads();
    // row e (128B), chunk c (16B, d=8c..8c+7) stored at slot c^(e&7)
    for (int j = tid; j < 4096; j += 256) {
        int e = j >> 6, dpos = j & 63;
        int slot = dpos >> 3, jj = dpos & 7;
        int d = ((slot ^ (e & 7)) << 3) + jj;
        bTsw[(size_t)o * 4096 + j] = (__bf16)s[d * 65 + e];
    }
    // -cproj packed: [etile][l5][reg] -> e-row = 32*et + 4*l5 + (reg&3) + 8*(reg>>2)
    if (tid < 64) {
        int et = tid >> 5, rem = tid & 31, l5 = rem >> 4, reg = rem & 15;
        int row = et * 32 + l5 * 4 + (reg & 3) + ((reg >> 2) << 3);
        float acc = 0.f;
        for (int d = 0; d < 64; ++d) acc += s[d * 65 + row] * centers[o * 64 + d];
        ncpk[o * 64 + tid] = -acc;
    }
}

// ---- main: wave = 128 b x 8 o, 32x32x16 MFMA. sX block-shared (1 barrier);
//      A + cp DMA'd per-o into wave-private LDS (async, batched, no barriers). ----
__global__ void __launch_bounds__(256)
__attribute__((amdgpu_waves_per_eu(2, 2)))
k_main(const float* __restrict__ x, const __bf16* __restrict__ bTsw,
       const float* __restrict__ ncpk, float* __restrict__ out) {
    __shared__ __align__(16) __bf16 sX[128 * 64];       // 16 KB, xor-swizzled
    __shared__ __align__(16) __bf16 sA[4][64 * 64];     // 8 KB per wave (private)
    __shared__ __align__(16) float  sCp[4][64];         // 256 B per wave

    const int tid = threadIdx.x, wq = tid >> 6, lane = tid & 63;
    const int l31 = lane & 31, l5 = lane >> 5;
    const int bbase = blockIdx.x * 128;
    const int o0 = blockIdx.y * 32 + wq * 8;

    // stage x fp32 -> bf16, chunk (rb, c) at slot c^(rb&7)
#pragma unroll
    for (int i = 0; i < 4; ++i) {
        int id = i * 256 + tid, rb = id >> 3, c = id & 7;
        const float* xp = x + (size_t)(bbase + rb) * 64 + c * 8;
        float4 v0 = *(const float4*)xp, v1 = *(const float4*)(xp + 4);
        bf16x8 f;
        f[0] = (__bf16)v0.x; f[1] = (__bf16)v0.y; f[2] = (__bf16)v0.z; f[3] = (__bf16)v0.w;
        f[4] = (__bf16)v1.x; f[5] = (__bf16)v1.y; f[6] = (__bf16)v1.z; f[7] = (__bf16)v1.w;
        *(bf16x8*)(sX + rb * 64 + ((c ^ (rb & 7)) << 3)) = f;
    }
    __syncthreads();                                    // the only block barrier

    // resident x-fragments: B-operand, lane: n = l31, k = l5*8+j (K=16/step)
    bf16x8 xf[4][4];                                    // [btile][kstep] = 64 VGPR
#pragma unroll
    for (int bt = 0; bt < 4; ++bt)
#pragma unroll
        for (int k = 0; k < 4; ++k) {
            int row = bt * 32 + l31, c = k * 2 + l5;
            xf[bt][k] = *(const bf16x8*)(sX + row * 64 + ((c ^ (row & 7)) << 3));
        }

    __bf16* myA  = &sA[wq][0];
    float*  myCp = &sCp[wq][0];

    for (int oi = 0; oi < 8; ++oi) {
        const int o = o0 + oi;
        const __bf16* gA = bTsw + (size_t)o * 4096 + lane * 8;
#pragma unroll
        for (int cll = 0; cll < 8; ++cll)               // 8 KB A-image, 9-deep async batch
            GLD16(gA + cll * 512, myA + cll * 512);
        GLD4(ncpk + o * 64 + lane, myCp);
        __builtin_amdgcn_sched_barrier(0);
        __builtin_amdgcn_s_waitcnt(0x0f70);             // vmcnt(0): DMA landed
        __builtin_amdgcn_sched_barrier(0);

        f32x4 qv[4] = {{0.f,0.f,0.f,0.f},{0.f,0.f,0.f,0.f},{0.f,0.f,0.f,0.f},{0.f,0.f,0.f,0.f}};
#pragma unroll
        for (int et = 0; et < 2; ++et) {
            f32x16 cpv;                                 // C-init = -cp in C-reg order
#pragma unroll
            for (int r4 = 0; r4 < 4; ++r4)
                ((f32x4*)&cpv)[r4] = *(const f32x4*)(myCp + et * 32 + l5 * 16 + r4 * 4);
            bf16x8 af[4];                               // A-operand: m = l31, k = l5*8+j
#pragma unroll
            for (int k = 0; k < 4; ++k) {
                int row = et * 32 + l31, c = k * 2 + l5;
                af[k] = *(const bf16x8*)(myA + row * 64 + ((c ^ (row & 7)) << 3));
            }
#pragma unroll
            for (int bt = 0; bt < 4; ++bt) {
                f32x16 acc = __builtin_amdgcn_mfma_f32_32x32x16_bf16(af[0], xf[bt][0], cpv, 0, 0, 0);
                acc = __builtin_amdgcn_mfma_f32_32x32x16_bf16(af[1], xf[bt][1], acc, 0, 0, 0);
                acc = __builtin_amdgcn_mfma_f32_32x32x16_bf16(af[2], xf[bt][2], acc, 0, 0, 0);
                acc = __builtin_amdgcn_mfma_f32_32x32x16_bf16(af[3], xf[bt][3], acc, 0, 0, 0);
#pragma unroll
                for (int j = 0; j < 16; ++j)            // qv += (y-cp)^2
                    qv[bt][j & 3] = fmaf(acc[j], acc[j], qv[bt][j & 3]);
            }
        }
        float q[4];
#pragma unroll
        for (int bt = 0; bt < 4; ++bt) {                // one shuffle per btile
            float qs = (qv[bt][0] + qv[bt][1]) + (qv[bt][2] + qv[bt][3]);
            qs += __shfl_xor(qs, 32, 64);
            q[bt] = qs;
        }
        float qA = l5 ? q[2] : q[0], qB = l5 ? q[3] : q[1];
        int bA = bbase + l5 * 64 + l31;                 // lane stores btiles {2*l5, 2*l5+1}
        out[(size_t)bA * 256 + o]        = __expf(-qA);
        out[(size_t)(bA + 32) * 256 + o] = __expf(-qB);
        __builtin_amdgcn_sched_barrier(0);              // pin: next DMA can't pass my reads
    }
}

extern "C" void kernel_launch(void* const* d_in, const int* in_sizes, int n_in,
                              void* d_out, int out_size, void* d_ws, size_t ws_size,
                              hipStream_t stream) {
    const float* x       = (const float*)d_in[0];   // [8192,64]
    const float* centers = (const float*)d_in[1];   // [256,1,64]
    const float* betas   = (const float*)d_in[2];   // [256,64,64]
    float* out = (float*)d_out;                     // [8192,256] fp32

    char* ws = (char*)d_ws;
    __bf16* bTsw = (__bf16*)ws;                     // 2 MB (swizzled A-images)
    float*  ncpk = (float*)(ws + 2 * (1 << 20));    // 64 KB (packed -cproj)

    k_prep<<<dim3(On),           dim3(256), 0, stream>>>(betas, centers, bTsw, ncpk);
    k_main<<<dim3(Bn / 128, On / 32), dim3(256), 0, stream>>>(x, bTsw, ncpk, out);
}